// Round 19
// baseline (356.642 us; speedup 1.0000x reference)
//
#include <hip/hip_runtime.h>

#define NN 50000
#define NE 800000
#define DD 128

typedef __attribute__((ext_vector_type(8))) short short8;
typedef __attribute__((ext_vector_type(4))) float f32x4;

__device__ inline unsigned short f2bf_rne(float f) {
  unsigned u = __float_as_uint(f);
  u += 0x7FFF + ((u >> 16) & 1);
  return (unsigned short)(u >> 16);
}
__device__ inline float bf2f(unsigned short h) {
  return __uint_as_float(((unsigned)h) << 16);
}
__device__ inline float bflo(unsigned u) { return __uint_as_float(u << 16); }
__device__ inline float bfhi(unsigned u) { return __uint_as_float(u & 0xffff0000u); }

// ------------------------------------------------- fused prologue
__global__ __launch_bounds__(256) void prologue(
    const float* __restrict__ Wl1, const float* __restrict__ Wl2,
    const float* __restrict__ Wp1,
    unsigned short* __restrict__ WTh, unsigned short* __restrict__ WTl,
    const float2* __restrict__ xin2, unsigned* __restrict__ xbf2,
    int* __restrict__ cnt) {
  const int tid = blockIdx.x * 256 + threadIdx.x;
  if (tid < NN) cnt[tid] = 0;
  if (tid < 8 * 16384) {
    const int g = tid >> 14, idx = tid & 16383;
    const int n = idx >> 7, k = idx & 127;
    const float* s;
    if (g < 3) s = Wl1 + (size_t)g * 16384;
    else if (g < 6) s = Wl2 + (size_t)(g - 3) * 16384;
    else s = Wp1 + (size_t)(g - 6) * 16384;
    const float v = s[k * 128 + n];
    const unsigned short hi = f2bf_rne(v);
    WTh[tid] = hi;
    WTl[tid] = f2bf_rne(v - bf2f(hi));
  }
  if (tid < NN * DD / 2) {
    const float2 v = xin2[tid];
    xbf2[tid] = (unsigned)f2bf_rne(v.x) | ((unsigned)f2bf_rne(v.y) << 16);
  }
}

// ------------------------------------------------- CSR build: histogram + rank
// 2 edges/thread: 2 independent atomic round-trips in flight; int2 rank store.
__global__ __launch_bounds__(256) void hist_rank(const int* __restrict__ dst,
                                                 int* __restrict__ cnt,
                                                 int* __restrict__ rank) {
  int e = (blockIdx.x * 256 + threadIdx.x) * 2;
  if (e + 2 <= NE) {
    const int2 d = *(const int2*)(dst + e);
    const int ra = atomicAdd(&cnt[d.x], 1);
    const int rb = atomicAdd(&cnt[d.y], 1);
    *(int2*)(rank + e) = make_int2(ra, rb);
  } else if (e < NE) {
    rank[e] = atomicAdd(&cnt[dst[e]], 1);
  }
}

// ------------------------------------------------- CSR build: scan (1 block)
__global__ __launch_bounds__(1024) void scan_nodes(const int* __restrict__ cnt,
                                                   int* __restrict__ offs) {
  __shared__ int wsum[16];
  __shared__ int wpre[16];
  const int t = threadIdx.x;
  const int lane = t & 63, wv = t >> 6;
  int carry = 0;
  for (int base = 0; base < NN; base += 8192) {
    const int i0 = base + t * 8;
    int4 a = make_int4(0, 0, 0, 0), b = make_int4(0, 0, 0, 0);
    if (i0 + 8 <= NN) {
      a = *(const int4*)(cnt + i0);
      b = *(const int4*)(cnt + i0 + 4);
    } else if (i0 < NN) {
      int tmp[8];
      for (int j = 0; j < 8; ++j) tmp[j] = (i0 + j < NN) ? cnt[i0 + j] : 0;
      a = make_int4(tmp[0], tmp[1], tmp[2], tmp[3]);
      b = make_int4(tmp[4], tmp[5], tmp[6], tmp[7]);
    }
    const int own = a.x + a.y + a.z + a.w + b.x + b.y + b.z + b.w;
    int inc = own;
#pragma unroll
    for (int d = 1; d < 64; d <<= 1) {
      int v = __shfl_up(inc, d, 64);
      if (lane >= d) inc += v;
    }
    if (lane == 63) wsum[wv] = inc;
    __syncthreads();
    if (t < 16) {
      int v = wsum[t];
      int p = v;
#pragma unroll
      for (int d = 1; d < 16; d <<= 1) {
        int u = __shfl_up(p, d, 16);
        if (t >= d) p += u;
      }
      wpre[t] = p - v;
      if (t == 15) wsum[15] = p;
    }
    __syncthreads();
    int run = carry + wpre[wv] + inc - own;
    const int o0 = run,      o1 = o0 + a.x, o2 = o1 + a.y, o3 = o2 + a.z;
    const int o4 = o3 + a.w, o5 = o4 + b.x, o6 = o5 + b.y, o7 = o6 + b.z;
    if (i0 + 8 <= NN) {
      *(int4*)(offs + i0)     = make_int4(o0, o1, o2, o3);
      *(int4*)(offs + i0 + 4) = make_int4(o4, o5, o6, o7);
    } else if (i0 < NN) {
      const int o[8] = {o0, o1, o2, o3, o4, o5, o6, o7};
      for (int j = 0; j < 8; ++j)
        if (i0 + j < NN) offs[i0 + j] = o[j];
    }
    carry += wsum[15];
    __syncthreads();
  }
  if (t == 0) offs[NN] = carry;
}

// ------------------------------------------------- CSR build: fill (8B packed recs)
__global__ __launch_bounds__(256) void csr_fill(
    const int* __restrict__ src, const int* __restrict__ dst,
    const float* __restrict__ ea, const int* __restrict__ offs,
    const int* __restrict__ rank, uint2* __restrict__ recs) {
  int e = blockIdx.x * 256 + threadIdx.x;
  if (e >= NE) return;
  int pos = offs[dst[e]] + rank[e];
  const unsigned s = (unsigned)src[e];
  const unsigned eb = (unsigned)f2bf_rne(ea[e]);
  recs[pos] = make_uint2(s | ((unsigned)e << 16),
                         ((unsigned)e >> 16) | (eb << 16));
}

// ------------------------------------------------- per-node aggregation
// 32 lanes/node (6250 blocks, max TLP); bf16 in AND out; 8-deep unroll.
__global__ __launch_bounds__(256) void aggregate(
    const unsigned short* __restrict__ xbf,
    const int* __restrict__ offs, const uint2* __restrict__ recs,
    const float4* __restrict__ We4, const float4* __restrict__ be4,
    unsigned* __restrict__ outbf2) {   // NN*DD/2 packed bf16 pairs
  const int slot = threadIdx.x >> 5, lane = threadIdx.x & 31;
  const int n = blockIdx.x * 8 + slot;
  if (n >= NN) return;
  const float4 wv = We4[lane], bv = be4[lane];
  float4 a0, a1, a2, a3;
  {
    const uint2 sq = *(const uint2*)(xbf + (size_t)n * DD + lane * 4);
    a0.x = bflo(sq.x); a0.y = bfhi(sq.x);
    a0.z = bflo(sq.y); a0.w = bfhi(sq.y);
  }
  a1 = make_float4(0.f, 0.f, 0.f, 0.f);
  a2 = make_float4(0.f, 0.f, 0.f, 0.f);
  a3 = make_float4(0.f, 0.f, 0.f, 0.f);
  const int beg = offs[n], end = offs[n + 1];
  int i = beg;
#define ACCQ(acc, rec, qq)                                                    \
  {                                                                           \
    const float ee = bf2f((unsigned short)((rec).y >> 16));                   \
    acc.x += fmaxf(fmaf(ee, wv.x, bv.x) + bflo((qq).x), 0.f);                 \
    acc.y += fmaxf(fmaf(ee, wv.y, bv.y) + bfhi((qq).x), 0.f);                 \
    acc.z += fmaxf(fmaf(ee, wv.z, bv.z) + bflo((qq).y), 0.f);                 \
    acc.w += fmaxf(fmaf(ee, wv.w, bv.w) + bfhi((qq).y), 0.f);                 \
  }
  for (; i + 8 <= end; i += 8) {
    uint2 r[8];
#pragma unroll
    for (int u = 0; u < 8; ++u) r[u] = recs[i + u];
    uint2 q[8];
#pragma unroll
    for (int u = 0; u < 8; ++u)
      q[u] = *(const uint2*)(xbf + (size_t)(r[u].x & 0xFFFFu) * DD + lane * 4);
    ACCQ(a0, r[0], q[0]) ACCQ(a1, r[1], q[1]) ACCQ(a2, r[2], q[2]) ACCQ(a3, r[3], q[3])
    ACCQ(a0, r[4], q[4]) ACCQ(a1, r[5], q[5]) ACCQ(a2, r[6], q[6]) ACCQ(a3, r[7], q[7])
  }
  for (; i + 4 <= end; i += 4) {
    uint2 r[4];
#pragma unroll
    for (int u = 0; u < 4; ++u) r[u] = recs[i + u];
    uint2 q[4];
#pragma unroll
    for (int u = 0; u < 4; ++u)
      q[u] = *(const uint2*)(xbf + (size_t)(r[u].x & 0xFFFFu) * DD + lane * 4);
    ACCQ(a0, r[0], q[0]) ACCQ(a1, r[1], q[1]) ACCQ(a2, r[2], q[2]) ACCQ(a3, r[3], q[3])
  }
  for (; i < end; ++i) {
    const uint2 r0 = recs[i];
    const uint2 q0 = *(const uint2*)(xbf + (size_t)(r0.x & 0xFFFFu) * DD + lane * 4);
    ACCQ(a0, r0, q0)
  }
#undef ACCQ
  a0.x += a1.x + a2.x + a3.x;
  a0.y += a1.y + a2.y + a3.y;
  a0.z += a1.z + a2.z + a3.z;
  a0.w += a1.w + a2.w + a3.w;
  const unsigned lo = (unsigned)f2bf_rne(a0.x) | ((unsigned)f2bf_rne(a0.y) << 16);
  const unsigned hi = (unsigned)f2bf_rne(a0.z) | ((unsigned)f2bf_rne(a0.w) << 16);
  uint2* orow = (uint2*)(outbf2 + (size_t)n * (DD / 2)) + lane;
  *orow = make_uint2(lo, hi);
}

// ------------------------------------------------- fused layer MLP
__global__ __launch_bounds__(256) void fused_mlp(
    const unsigned short* __restrict__ in,
    const unsigned short* __restrict__ W1h, const unsigned short* __restrict__ W1l,
    const unsigned short* __restrict__ W2h, const unsigned short* __restrict__ W2l,
    const float* __restrict__ b1, const float* __restrict__ b2,
    unsigned short* __restrict__ outbf) {
  __shared__ float hl[16][132];
  const int t = threadIdx.x;
  const int w = t >> 6, l = t & 63;
  const int lr = l & 15, kg = l >> 4;

  short8 B1h_[2][4], B1l_[2][4], B2h_[2][4], B2l_[2][4];
#pragma unroll
  for (int ct = 0; ct < 2; ++ct)
#pragma unroll
    for (int ks = 0; ks < 4; ++ks) {
      const size_t bo = (size_t)((w * 2 + ct) * 16 + lr) * DD + ks * 32 + kg * 8;
      B1h_[ct][ks] = *(const short8*)(W1h + bo);
      B1l_[ct][ks] = *(const short8*)(W1l + bo);
      B2h_[ct][ks] = *(const short8*)(W2h + bo);
      B2l_[ct][ks] = *(const short8*)(W2l + bo);
    }
  const float b1v0 = b1[(w * 2 + 0) * 16 + lr];
  const float b1v1 = b1[(w * 2 + 1) * 16 + lr];
  const float b2v0 = b2[(w * 2 + 0) * 16 + lr];
  const float b2v1 = b2[(w * 2 + 1) * 16 + lr];

  for (int c = blockIdx.x; c < NN / 16; c += gridDim.x) {
    f32x4 acc[2];
    // ---- GEMM1: A direct from bf16 (2 MFMA per ct)
    {
      const unsigned short* ap = in + ((size_t)c * 16 + lr) * DD + kg * 8;
      short8 ah[4];
#pragma unroll
      for (int ks = 0; ks < 4; ++ks) ah[ks] = *(const short8*)(ap + ks * 32);
      acc[0] = (f32x4){0.f, 0.f, 0.f, 0.f};
      acc[1] = (f32x4){0.f, 0.f, 0.f, 0.f};
#pragma unroll
      for (int ks = 0; ks < 4; ++ks)
#pragma unroll
        for (int ct = 0; ct < 2; ++ct) {
          acc[ct] = __builtin_amdgcn_mfma_f32_16x16x32_bf16(ah[ks], B1h_[ct][ks], acc[ct], 0, 0, 0);
          acc[ct] = __builtin_amdgcn_mfma_f32_16x16x32_bf16(ah[ks], B1l_[ct][ks], acc[ct], 0, 0, 0);
        }
    }
    // ---- h -> LDS (f32, lossless)
    __syncthreads();
#pragma unroll
    for (int ct = 0; ct < 2; ++ct) {
      const float bb = ct ? b1v1 : b1v0;
      const int col = (w * 2 + ct) * 16 + lr;
#pragma unroll
      for (int q = 0; q < 4; ++q)
        hl[kg * 4 + q][col] = fmaxf(acc[ct][q] + bb, 0.f);
    }
    __syncthreads();
    // ---- GEMM2: A from LDS (hi/lo split, 3 MFMA per ct)
    {
      float va[4][8];
#pragma unroll
      for (int ks = 0; ks < 4; ++ks) {
        *(float4*)&va[ks][0] = *(const float4*)&hl[lr][ks * 32 + kg * 8];
        *(float4*)&va[ks][4] = *(const float4*)&hl[lr][ks * 32 + kg * 8 + 4];
      }
      short8 ah[4], al[4];
#pragma unroll
      for (int ks = 0; ks < 4; ++ks)
#pragma unroll
        for (int j = 0; j < 8; ++j) {
          unsigned short h = f2bf_rne(va[ks][j]);
          ah[ks][j] = (short)h;
          al[ks][j] = (short)f2bf_rne(va[ks][j] - bf2f(h));
        }
      acc[0] = (f32x4){0.f, 0.f, 0.f, 0.f};
      acc[1] = (f32x4){0.f, 0.f, 0.f, 0.f};
#pragma unroll
      for (int ks = 0; ks < 4; ++ks)
#pragma unroll
        for (int ct = 0; ct < 2; ++ct) {
          acc[ct] = __builtin_amdgcn_mfma_f32_16x16x32_bf16(ah[ks], B2h_[ct][ks], acc[ct], 0, 0, 0);
          acc[ct] = __builtin_amdgcn_mfma_f32_16x16x32_bf16(ah[ks], B2l_[ct][ks], acc[ct], 0, 0, 0);
          acc[ct] = __builtin_amdgcn_mfma_f32_16x16x32_bf16(al[ks], B2h_[ct][ks], acc[ct], 0, 0, 0);
        }
    }
    // ---- epilogue (bf16)
#pragma unroll
    for (int ct = 0; ct < 2; ++ct) {
      const float bb = ct ? b2v1 : b2v0;
      const int col = (w * 2 + ct) * 16 + lr;
#pragma unroll
      for (int q = 0; q < 4; ++q) {
        const float v = fmaxf(acc[ct][q] + bb, 0.f);
        outbf[((size_t)c * 16 + kg * 4 + q) * DD + col] = f2bf_rne(v);
      }
    }
  }
}

// ------------------------------------------------- fused predictor GEMMs
__global__ __launch_bounds__(256) void gemm_pred2(
    const unsigned short* __restrict__ in,
    const unsigned short* __restrict__ W1h, const unsigned short* __restrict__ W1l,
    const unsigned short* __restrict__ W2h, const unsigned short* __restrict__ W2l,
    const float* __restrict__ bp1,
    unsigned short* __restrict__ P1bf, unsigned short* __restrict__ P2bf) {
  const int t = threadIdx.x;
  const int w = t >> 6, l = t & 63;
  const int lr = l & 15, kg = l >> 4;

  short8 B1h[2][4], B1l[2][4], B2h[2][4], B2l[2][4];
#pragma unroll
  for (int ct = 0; ct < 2; ++ct)
#pragma unroll
    for (int ks = 0; ks < 4; ++ks) {
      const size_t bo = (size_t)((w * 2 + ct) * 16 + lr) * DD + ks * 32 + kg * 8;
      B1h[ct][ks] = *(const short8*)(W1h + bo);
      B1l[ct][ks] = *(const short8*)(W1l + bo);
      B2h[ct][ks] = *(const short8*)(W2h + bo);
      B2l[ct][ks] = *(const short8*)(W2l + bo);
    }
  float bv0 = bp1[(w * 2 + 0) * 16 + lr];
  float bv1 = bp1[(w * 2 + 1) * 16 + lr];

  for (int c = blockIdx.x; c < NN / 16; c += gridDim.x) {
    const unsigned short* ap = in + ((size_t)c * 16 + lr) * DD + kg * 8;
    short8 ah[4];
#pragma unroll
    for (int ks = 0; ks < 4; ++ks) ah[ks] = *(const short8*)(ap + ks * 32);
    f32x4 acc1[2], acc2[2];
    acc1[0] = (f32x4){0.f, 0.f, 0.f, 0.f};
    acc1[1] = (f32x4){0.f, 0.f, 0.f, 0.f};
    acc2[0] = (f32x4){0.f, 0.f, 0.f, 0.f};
    acc2[1] = (f32x4){0.f, 0.f, 0.f, 0.f};
#pragma unroll
    for (int ks = 0; ks < 4; ++ks) {
#pragma unroll
      for (int ct = 0; ct < 2; ++ct) {
        acc1[ct] = __builtin_amdgcn_mfma_f32_16x16x32_bf16(ah[ks], B1h[ct][ks], acc1[ct], 0, 0, 0);
        acc1[ct] = __builtin_amdgcn_mfma_f32_16x16x32_bf16(ah[ks], B1l[ct][ks], acc1[ct], 0, 0, 0);
        acc2[ct] = __builtin_amdgcn_mfma_f32_16x16x32_bf16(ah[ks], B2h[ct][ks], acc2[ct], 0, 0, 0);
        acc2[ct] = __builtin_amdgcn_mfma_f32_16x16x32_bf16(ah[ks], B2l[ct][ks], acc2[ct], 0, 0, 0);
      }
    }
#pragma unroll
    for (int ct = 0; ct < 2; ++ct) {
      const int col = (w * 2 + ct) * 16 + lr;
      const float bb = ct ? bv1 : bv0;
#pragma unroll
      for (int q4 = 0; q4 < 4; ++q4) {
        const size_t r = (size_t)c * 16 + kg * 4 + q4;
        P1bf[r * DD + col] = f2bf_rne(acc1[ct][q4]);
        P2bf[r * DD + col] = f2bf_rne(acc2[ct][q4] + bb);
      }
    }
  }
}

// ------------------------------------------------- final edge pass
// 32-lane slot/node; slot splits into 4 x 8-lane sub-groups, one edge each,
// 16 elems/lane (2 x uint4) -> 3-stage reduce. 2 edges/sub batch (8/slot).
__global__ __launch_bounds__(256) void edge_out(
    const unsigned short* __restrict__ P1bf, const unsigned short* __restrict__ P2bf,
    const int* __restrict__ offs, const uint2* __restrict__ recs,
    const float* __restrict__ Wp2,
    const float* __restrict__ bp2, float* __restrict__ out) {
  const int slot = threadIdx.x >> 5, lane = threadIdx.x & 31;
  const int sub = lane >> 3, sl = lane & 7;
  const int n = blockIdx.x * 8 + slot;
  if (n >= NN) return;
  const float bb = bp2[0];
  float w[16], p2[16];
  {
    const float4* wp = (const float4*)(Wp2 + sl * 16);
    *(float4*)&w[0] = wp[0];  *(float4*)&w[4] = wp[1];
    *(float4*)&w[8] = wp[2];  *(float4*)&w[12] = wp[3];
    const uint4* pq = (const uint4*)(P2bf + (size_t)n * DD + sl * 16);
    const uint4 a = pq[0], b = pq[1];
    p2[0] = bflo(a.x);  p2[1] = bfhi(a.x);  p2[2] = bflo(a.y);  p2[3] = bfhi(a.y);
    p2[4] = bflo(a.z);  p2[5] = bfhi(a.z);  p2[6] = bflo(a.w);  p2[7] = bfhi(a.w);
    p2[8] = bflo(b.x);  p2[9] = bfhi(b.x);  p2[10] = bflo(b.y); p2[11] = bfhi(b.y);
    p2[12] = bflo(b.z); p2[13] = bfhi(b.z); p2[14] = bflo(b.w); p2[15] = bfhi(b.w);
  }
  const int beg = offs[n], end = offs[n + 1];
  int i = beg;
#define DOT16(vv, qa, qb)                                                     \
  {                                                                           \
    vv = fmaxf(bflo((qa).x) + p2[0], 0.f) * w[0]                              \
       + fmaxf(bfhi((qa).x) + p2[1], 0.f) * w[1]                              \
       + fmaxf(bflo((qa).y) + p2[2], 0.f) * w[2]                              \
       + fmaxf(bfhi((qa).y) + p2[3], 0.f) * w[3]                              \
       + fmaxf(bflo((qa).z) + p2[4], 0.f) * w[4]                              \
       + fmaxf(bfhi((qa).z) + p2[5], 0.f) * w[5]                              \
       + fmaxf(bflo((qa).w) + p2[6], 0.f) * w[6]                              \
       + fmaxf(bfhi((qa).w) + p2[7], 0.f) * w[7]                              \
       + fmaxf(bflo((qb).x) + p2[8], 0.f) * w[8]                              \
       + fmaxf(bfhi((qb).x) + p2[9], 0.f) * w[9]                              \
       + fmaxf(bflo((qb).y) + p2[10], 0.f) * w[10]                            \
       + fmaxf(bfhi((qb).y) + p2[11], 0.f) * w[11]                            \
       + fmaxf(bflo((qb).z) + p2[12], 0.f) * w[12]                            \
       + fmaxf(bfhi((qb).z) + p2[13], 0.f) * w[13]                            \
       + fmaxf(bflo((qb).w) + p2[14], 0.f) * w[14]                            \
       + fmaxf(bfhi((qb).w) + p2[15], 0.f) * w[15];                           \
  }
#define EID(r) (((r).x >> 16) | (((r).y & 0xFFFFu) << 16))
  for (; i + 8 <= end; i += 8) {
    const uint2 r0 = recs[i + sub], r1 = recs[i + 4 + sub];
    const uint4* q0p = (const uint4*)(P1bf + (size_t)(r0.x & 0xFFFFu) * DD + sl * 16);
    const uint4* q1p = (const uint4*)(P1bf + (size_t)(r1.x & 0xFFFFu) * DD + sl * 16);
    const uint4 q0a = q0p[0], q0b = q0p[1];
    const uint4 q1a = q1p[0], q1b = q1p[1];
    float v0, v1;
    DOT16(v0, q0a, q0b)
    DOT16(v1, q1a, q1b)
#pragma unroll
    for (int m = 4; m >= 1; m >>= 1) {
      v0 += __shfl_xor(v0, m, 64);
      v1 += __shfl_xor(v1, m, 64);
    }
    if (sl == 0) {
      out[EID(r0)] = v0 + bb;
      out[EID(r1)] = v1 + bb;
    }
  }
  for (; i + 4 <= end; i += 4) {
    const uint2 r0 = recs[i + sub];
    const uint4* q0p = (const uint4*)(P1bf + (size_t)(r0.x & 0xFFFFu) * DD + sl * 16);
    const uint4 q0a = q0p[0], q0b = q0p[1];
    float v0;
    DOT16(v0, q0a, q0b)
#pragma unroll
    for (int m = 4; m >= 1; m >>= 1) v0 += __shfl_xor(v0, m, 64);
    if (sl == 0) out[EID(r0)] = v0 + bb;
  }
  if (i < end) {
    const int e = i + sub;
    const bool act = e < end;
    const uint2 r0 = recs[act ? e : i];
    const uint4* q0p = (const uint4*)(P1bf + (size_t)(r0.x & 0xFFFFu) * DD + sl * 16);
    const uint4 q0a = q0p[0], q0b = q0p[1];
    float v0;
    DOT16(v0, q0a, q0b)
#pragma unroll
    for (int m = 4; m >= 1; m >>= 1) v0 += __shfl_xor(v0, m, 64);
    if (sl == 0 && act) out[EID(r0)] = v0 + bb;
  }
#undef DOT16
#undef EID
}

// ---------------------------------------------------------------- launch
extern "C" void kernel_launch(void* const* d_in, const int* in_sizes, int n_in,
                              void* d_out, int out_size, void* d_ws, size_t ws_size,
                              hipStream_t stream) {
  const float* x_in = (const float*)d_in[0];
  const float* ea   = (const float*)d_in[1];
  const int*   ei   = (const int*)d_in[2];   // integer inputs arrive as int32
  const float* Wl1 = (const float*)d_in[3];
  const float* bl1 = (const float*)d_in[4];
  const float* Wl2 = (const float*)d_in[5];
  const float* bl2 = (const float*)d_in[6];
  const float* We  = (const float*)d_in[7];
  const float* be  = (const float*)d_in[8];
  const float* Wp1 = (const float*)d_in[9];
  const float* bp1 = (const float*)d_in[10];
  const float* Wp2 = (const float*)d_in[11];
  const float* bp2 = (const float*)d_in[12];
  const int* src = ei;
  const int* dst = ei + NE;

  // workspace layout (~75 MB)
  float* bufA   = (float*)d_ws;                    // NN*DD region (used as bf16)
  float* bufB   = bufA + (size_t)NN * DD;          // NN*DD region (used as bf16)
  int*   cnt    = (int*)(bufB + (size_t)NN * DD);  // NN
  int*   offs   = cnt + NN;                        // NN+1
  int*   rank   = offs + NN + 1;                   // NE
  uint2* recs   = (uint2*)(((uintptr_t)(rank + NE) + 15) & ~(uintptr_t)15); // NE x 8B
  unsigned short* WTh = (unsigned short*)(recs + NE);   // 8*16384 bf16
  unsigned short* WTl = WTh + 8 * 16384;                // 8*16384 bf16
  unsigned short* xbf = WTl + 8 * 16384;                // NN*DD bf16 (x0..x3)
  unsigned short* agg = (unsigned short*)bufA;          // NN*DD bf16 (agg out / P1bf)
  unsigned short* p2b = (unsigned short*)bufB;          // NN*DD bf16 (P2bf)

  // fused prologue + CSR build (per-launch, deterministic)
  prologue<<<(NN * DD / 2 + 255) / 256, 256, 0, stream>>>(
      Wl1, Wl2, Wp1, WTh, WTl, (const float2*)x_in, (unsigned*)xbf, cnt);
  hist_rank<<<(NE / 2 + 255) / 256, 256, 0, stream>>>(dst, cnt, rank);
  scan_nodes<<<1, 1024, 0, stream>>>(cnt, offs);
  csr_fill<<<NE / 256, 256, 0, stream>>>(src, dst, ea, offs, rank, recs);

  const int GB = 1024;            // gemm grid: ~3 chunks/block
  const int AB = (NN + 7) / 8;    // 6250 blocks: 32-lane slot/node (max TLP)
#define WH(g) (WTh + (size_t)(g) * 16384)
#define WL(g) (WTl + (size_t)(g) * 16384)

  // L0: agg(xbf=x0)->agg(bf16); mlp agg -> xbf (x1)
  aggregate<<<AB, 256, 0, stream>>>(
      xbf, offs, recs, (const float4*)We, (const float4*)be, (unsigned*)agg);
  fused_mlp<<<GB, 256, 0, stream>>>(
      agg, WH(0), WL(0), WH(3), WL(3), bl1, bl2, xbf);
  // L1
  aggregate<<<AB, 256, 0, stream>>>(
      xbf, offs, recs, (const float4*)(We + DD), (const float4*)(be + DD), (unsigned*)agg);
  fused_mlp<<<GB, 256, 0, stream>>>(
      agg, WH(1), WL(1), WH(4), WL(4), bl1 + DD, bl2 + DD, xbf);
  // L2
  aggregate<<<AB, 256, 0, stream>>>(
      xbf, offs, recs, (const float4*)(We + 2 * DD), (const float4*)(be + 2 * DD), (unsigned*)agg);
  fused_mlp<<<GB, 256, 0, stream>>>(
      agg, WH(2), WL(2), WH(5), WL(5), bl1 + 2 * DD, bl2 + 2 * DD, xbf);
  // predictor: x3 = xbf.  P1bf -> agg (bufA), P2bf -> p2b (bufB).
  gemm_pred2<<<GB, 256, 0, stream>>>(xbf, WH(6), WL(6), WH(7), WL(7), bp1,
                                     agg, p2b);
  edge_out<<<AB, 256, 0, stream>>>(
      agg, p2b, offs, recs, Wp2, bp2, (float*)d_out);
}